// Round 21
// baseline (4275.448 us; speedup 1.0000x reference)
//
#include <hip/hip_runtime.h>
#include <stdint.h>

#define T_STEPS 100
#define BATCH   256
#define N_IN    2048
#define N_H     1024
#define N_OUT   10
#define M_TOT   (T_STEPS * BATCH)   // 25600
#define KC      384                 // OpenBLAS SGEMM_DEFAULT_Q (Haswell/Zen)

// async global->LDS, 16B per lane, linear LDS dest (wave base + lane*16)
#define GLD16(gp, lp)                                                  \
  __builtin_amdgcn_global_load_lds(                                    \
      (const __attribute__((address_space(1))) void*)(gp),             \
      (__attribute__((address_space(3))) void*)(lp), 16, 0, 0)

// ---------------------------------------------------------------------------
// GEMM1 panel pass (one dispatch per KC panel; 6 total).
// Bit-exact contract (R9/R14/R16/R19/R20-verified): per C element each panel
// is a k-ascending FMA register chain from 0; joins are one f32 add per panel
// boundary in pass order (C RMW between dispatches); bias after last.
// Tile 128m x 128n, BK=32, 512 threads, 8x4 microtile.
// Staging via global_load_lds width-16 (4 instr/thread/step, no ds_write,
// no VGPR round-trip). LDS linear row-major [row][32]; B global source is
// inverse-XOR-swizzled (quad q <- q ^ ((n>>2)&7)) so swizzled reads are
// 4-way instead of 32-way conflicted (rule #21: both-sides-or-neither).
// XCD map: xcd=id&7 owns an m-strip; 8 n-tiles of an m-tile consecutive.
// ---------------------------------------------------------------------------
__global__ __launch_bounds__(512, 8) void gemm1_panel(
    const float* __restrict__ A, const float* __restrict__ Bm,
    const float* __restrict__ bias, float* __restrict__ C,
    int ks, int klen, int first, int last) {
  __shared__ float As[128 * 32];   // 16 KB, linear [m][32]
  __shared__ float Bs[128 * 32];   // 16 KB, linear [n][32] (content swizzled)
  const int tid = threadIdx.x;
  const int id = blockIdx.x;
  const int xcd = id & 7;
  const int j = id >> 3;               // 0..199 sequential per XCD
  const int m0 = (xcd * 25 + (j >> 3)) * 128;
  const int n0 = (j & 7) * 128;
  const int tx = tid & 31;        // col group (4 cols)
  const int ty = tid >> 5;        // row group (8 rows)

  // staging: slot s in [0,1024) covers LDS floats [4s,4s+4); thread owns
  // slots tid and tid+512 of each array. row = s>>3, quad = s&7.
  const int s0 = tid, s1 = tid + 512;
  const int mA0 = s0 >> 3, qA0 = s0 & 7;
  const int mA1 = s1 >> 3, qA1 = s1 & 7;
  const int nB0 = s0 >> 3, qB0 = (s0 & 7) ^ ((nB0 >> 2) & 7);
  const int nB1 = s1 >> 3, qB1 = (s1 & 7) ^ ((nB1 >> 2) & 7);
  const float* gA0 = &A[(size_t)(m0 + mA0) * N_IN + ks + 4 * qA0];
  const float* gA1 = &A[(size_t)(m0 + mA1) * N_IN + ks + 4 * qA1];
  const float* gB0 = &Bm[(size_t)(n0 + nB0) * N_IN + ks + 4 * qB0];
  const float* gB1 = &Bm[(size_t)(n0 + nB1) * N_IN + ks + 4 * qB1];
  float* lA0 = &As[s0 * 4];
  float* lA1 = &As[s1 * 4];
  float* lB0 = &Bs[s0 * 4];
  float* lB1 = &Bs[s1 * 4];

  float acc[8][4];
#pragma unroll
  for (int i = 0; i < 8; i++)
#pragma unroll
    for (int j2 = 0; j2 < 4; j2++) acc[i][j2] = 0.f;

  const int bswz = tx & 7;   // == ((tx*4+jj)>>2)&7 for jj in 0..3
  const int nsteps = klen >> 5;
  for (int s = 0; s < nsteps; ++s) {
    const int off = s << 5;
    GLD16(gA0 + off, lA0);
    GLD16(gA1 + off, lA1);
    GLD16(gB0 + off, lB0);
    GLD16(gB1 + off, lB1);
    __syncthreads();   // drains vmcnt -> staged tiles visible
#pragma unroll
    for (int q4 = 0; q4 < 8; ++q4) {
      float4 b4[4];
#pragma unroll
      for (int jj = 0; jj < 4; ++jj) {
        const int n = tx * 4 + jj;
        b4[jj] = *(const float4*)&Bs[n * 32 + 4 * (q4 ^ bswz)];
      }
#pragma unroll
      for (int i = 0; i < 8; ++i) {
        const float4 a4 = *(const float4*)&As[(ty * 8 + i) * 32 + 4 * q4];
#pragma unroll
        for (int jj = 0; jj < 4; ++jj) {
          acc[i][jj] = __builtin_fmaf(a4.x, b4[jj].x, acc[i][jj]);
          acc[i][jj] = __builtin_fmaf(a4.y, b4[jj].y, acc[i][jj]);
          acc[i][jj] = __builtin_fmaf(a4.z, b4[jj].z, acc[i][jj]);
          acc[i][jj] = __builtin_fmaf(a4.w, b4[jj].w, acc[i][jj]);
        }
      }
    }
    __syncthreads();
  }
  // epilogue: join with previous panels (one add), bias after last panel
#pragma unroll
  for (int i = 0; i < 8; i++) {
    const int m = m0 + ty * 8 + i;
    const int n1 = n0 + tx * 4;
    float4* cp = (float4*)&C[(size_t)m * N_H + n1];
    float4 v;
    v.x = acc[i][0]; v.y = acc[i][1]; v.z = acc[i][2]; v.w = acc[i][3];
    if (!first) {
      const float4 o = *cp;
      v.x = __fadd_rn(o.x, v.x); v.y = __fadd_rn(o.y, v.y);
      v.z = __fadd_rn(o.z, v.z); v.w = __fadd_rn(o.w, v.w);
    }
    if (last) {
      v.x = __fadd_rn(v.x, bias[n1 + 0]); v.y = __fadd_rn(v.y, bias[n1 + 1]);
      v.z = __fadd_rn(v.z, bias[n1 + 2]); v.w = __fadd_rn(v.w, bias[n1 + 3]);
    }
    *cp = v;
  }
}

// ---------------------------------------------------------------------------
// Scan1: strict numpy op order (no fma): mem = ((0.9*mem) + cur) - reset.
// Spikes -> packed 64-bit ballot masks.
// ---------------------------------------------------------------------------
__global__ __launch_bounds__(256) void scan1_kernel(
    const float* __restrict__ cur1, unsigned long long* __restrict__ spkbits) {
  const int b = blockIdx.x >> 2;
  const int h = (blockIdx.x & 3) * 256 + threadIdx.x;
  const int lane = threadIdx.x & 63;
  const int word = h >> 6;  // 0..15
  float mem = 0.f;
  for (int t = 0; t < T_STEPS; ++t) {
    const float c = cur1[((size_t)t * BATCH + b) * N_H + h];
    const float reset = (mem > 1.0f) ? 1.0f : 0.0f;   // previous mem
    mem = __fsub_rn(__fadd_rn(__fmul_rn(0.9f, mem), c), reset);
    const unsigned long long msk = __ballot(mem > 1.0f);
    if (lane == 0) spkbits[((size_t)t * BATCH + b) * 16 + word] = msk;
  }
}

// ---------------------------------------------------------------------------
// cur2 (parallel over t,b,o): 3-panel k-ascending FMA chains —
// s1=[0,384), s2=[384,768), s3=[768,1024); cur2 = ((s1+s2)+s3) + b2[o].
// ---------------------------------------------------------------------------
__global__ __launch_bounds__(256) void cur2_kernel(
    const unsigned long long* __restrict__ spkbits,
    const float* __restrict__ W2, const float* __restrict__ b2,
    float* __restrict__ cur2) {
  const int g = blockIdx.x * 256 + threadIdx.x;   // ((t*256)+b)*10 + o
  const int tb = g / N_OUT;                       // t*256 + b
  const int o = g - tb * N_OUT;
  unsigned long long w[16];
#pragma unroll
  for (int i = 0; i < 16; i++) w[i] = spkbits[(size_t)tb * 16 + i];
  const float* W2o = &W2[(size_t)o * N_H];
  float s1 = 0.f, s2 = 0.f, s3 = 0.f;
#pragma unroll 8
  for (int h = 0; h < KC; ++h) {
    const float spk = ((w[h >> 6] >> (h & 63)) & 1ull) ? 1.0f : 0.0f;
    s1 = __builtin_fmaf(spk, W2o[h], s1);
  }
#pragma unroll 8
  for (int h = KC; h < 2 * KC; ++h) {
    const float spk = ((w[h >> 6] >> (h & 63)) & 1ull) ? 1.0f : 0.0f;
    s2 = __builtin_fmaf(spk, W2o[h], s2);
  }
#pragma unroll 8
  for (int h = 2 * KC; h < N_H; ++h) {
    const float spk = ((w[h >> 6] >> (h & 63)) & 1ull) ? 1.0f : 0.0f;
    s3 = __builtin_fmaf(spk, W2o[h], s3);
  }
  cur2[g] = __fadd_rn(__fadd_rn(__fadd_rn(s1, s2), s3), b2[o]);
}

// ---------------------------------------------------------------------------
// Scan2: strict mem2 scan over t per (b,o); writes spk2 + final mem2 (f32).
// ---------------------------------------------------------------------------
__global__ __launch_bounds__(256) void scan2_kernel(
    const float* __restrict__ cur2, float* __restrict__ out) {
  const int g = blockIdx.x * 256 + threadIdx.x;   // b*10 + o
  float m = 0.f;
  for (int t = 0; t < T_STEPS; ++t) {
    const float c = cur2[(size_t)t * (BATCH * N_OUT) + g];
    const float reset = (m > 1.0f) ? 1.0f : 0.0f;   // previous mem2
    m = __fsub_rn(__fadd_rn(__fmul_rn(0.9f, m), c), reset);
    out[(size_t)t * (BATCH * N_OUT) + g] = (m > 1.0f) ? 1.0f : 0.0f;
  }
  out[(size_t)T_STEPS * (BATCH * N_OUT) + g] = m;
}

// ---------------------------------------------------------------------------
extern "C" void kernel_launch(void* const* d_in, const int* in_sizes, int n_in,
                              void* d_out, int out_size, void* d_ws, size_t ws_size,
                              hipStream_t stream) {
  const float* x  = (const float*)d_in[0];   // [T, B, N_IN]  f32
  const float* W1 = (const float*)d_in[1];   // [N_H, N_IN]   f32
  const float* b1 = (const float*)d_in[2];   // [N_H]         f32
  const float* W2 = (const float*)d_in[3];   // [N_OUT, N_H]  f32
  const float* b2 = (const float*)d_in[4];   // [N_OUT]       f32
  float* out = (float*)d_out;  // f32: spk2[100,256,10] ++ mem2[256,10]

  // ws: cur1 f32 (104.9MB) | bits (3.3MB) | cur2 f32 (1.02MB)
  char* p = (char*)d_ws;
  float* cur1 = (float*)p;                           p += (size_t)M_TOT * N_H * 4;
  unsigned long long* bits = (unsigned long long*)p; p += (size_t)M_TOT * 16 * 8;
  float* cur2 = (float*)p;

  const int nblk = (M_TOT / 128) * (N_H / 128);   // 1600
  for (int ks = 0; ks < N_IN; ks += KC) {
    const int klen = (ks + KC <= N_IN) ? KC : (N_IN - ks);
    gemm1_panel<<<nblk, 512, 0, stream>>>(x, W1, b1, cur1, ks, klen,
                                          ks == 0 ? 1 : 0,
                                          (ks + klen == N_IN) ? 1 : 0);
  }
  scan1_kernel<<<BATCH * (N_H / 256), 256, 0, stream>>>(cur1, bits);
  cur2_kernel<<<(M_TOT * N_OUT) / 256, 256, 0, stream>>>(bits, W2, b2, cur2);
  scan2_kernel<<<(BATCH * N_OUT) / 256, 256, 0, stream>>>(cur2, out);
}

// Round 22
// 1547.359 us; speedup vs baseline: 2.7631x; 2.7631x over previous
//
#include <hip/hip_runtime.h>
#include <stdint.h>

#define T_STEPS 100
#define BATCH   256
#define N_IN    2048
#define N_H     1024
#define N_OUT   10
#define M_TOT   (T_STEPS * BATCH)   // 25600
#define KC      384                 // OpenBLAS SGEMM_DEFAULT_Q (Haswell/Zen)

// ---------------------------------------------------------------------------
// GEMM1 panel pass (one dispatch per KC panel; 6 total).
// Bit-exact contract (R9/R14/R16/R19/R20-verified): per C element each panel
// is a k-ascending FMA register chain from 0; joins are one f32 add per panel
// boundary in pass order (C RMW between dispatches); bias after last.
// Tile 128m x 128n, BK=32, 512 threads, 8x4 microtile -> 32 VGPR acc;
// __launch_bounds__(512,8): 4 blocks/CU. Best measured config (R20).
// XCD map: xcd=id&7 owns an m-strip; 8 n-tiles of an m-tile consecutive.
// ---------------------------------------------------------------------------
__global__ __launch_bounds__(512, 8) void gemm1_panel(
    const float* __restrict__ A, const float* __restrict__ Bm,
    const float* __restrict__ bias, float* __restrict__ C,
    int ks, int klen, int first, int last) {
  __shared__ float As[32][132];   // [k][m], +4 pad (16.9 KB)
  __shared__ float Bs[32][132];   // [k][n]          (16.9 KB)
  const int tid = threadIdx.x;
  const int id = blockIdx.x;
  const int xcd = id & 7;
  const int j = id >> 3;               // 0..199 sequential per XCD
  const int m0 = (xcd * 25 + (j >> 3)) * 128;
  const int n0 = (j & 7) * 128;
  const int tx = tid & 31;        // col group (4 cols)
  const int ty = tid >> 5;        // row group (8 rows)
  const int lrow = tid >> 2;      // 0..127
  const int lc8 = (tid & 3) * 8;  // 0,8,16,24

  // hoisted per-thread global pointers
  const float* pA = &A[(size_t)(m0 + lrow) * N_IN + ks + lc8];
  const float* pB = &Bm[(size_t)(n0 + lrow) * N_IN + ks + lc8];

  float acc[8][4];
#pragma unroll
  for (int i = 0; i < 8; i++)
#pragma unroll
    for (int j2 = 0; j2 < 4; j2++) acc[i][j2] = 0.f;

  for (int kk = 0; kk < klen; kk += 32) {
    // stage A tile (128x32) and B tile (128x32): 2 float4 each per thread
    const float4 av0 = *(const float4*)(pA + kk);
    const float4 av1 = *(const float4*)(pA + kk + 4);
    const float4 bv0 = *(const float4*)(pB + kk);
    const float4 bv1 = *(const float4*)(pB + kk + 4);
    As[lc8 + 0][lrow] = av0.x; As[lc8 + 1][lrow] = av0.y;
    As[lc8 + 2][lrow] = av0.z; As[lc8 + 3][lrow] = av0.w;
    As[lc8 + 4][lrow] = av1.x; As[lc8 + 5][lrow] = av1.y;
    As[lc8 + 6][lrow] = av1.z; As[lc8 + 7][lrow] = av1.w;
    Bs[lc8 + 0][lrow] = bv0.x; Bs[lc8 + 1][lrow] = bv0.y;
    Bs[lc8 + 2][lrow] = bv0.z; Bs[lc8 + 3][lrow] = bv0.w;
    Bs[lc8 + 4][lrow] = bv1.x; Bs[lc8 + 5][lrow] = bv1.y;
    Bs[lc8 + 6][lrow] = bv1.z; Bs[lc8 + 7][lrow] = bv1.w;
    __syncthreads();
#pragma unroll
    for (int k = 0; k < 32; k++) {
      float a[8], b[4];
      *(float4*)&a[0] = *(const float4*)&As[k][ty * 8];
      *(float4*)&a[4] = *(const float4*)&As[k][ty * 8 + 4];
      *(float4*)&b[0] = *(const float4*)&Bs[k][tx * 4];
#pragma unroll
      for (int i = 0; i < 8; i++)
#pragma unroll
        for (int j2 = 0; j2 < 4; j2++)
          acc[i][j2] = __builtin_fmaf(a[i], b[j2], acc[i][j2]);
    }
    __syncthreads();
  }
  // epilogue: join with previous panels (one add), bias after last panel
#pragma unroll
  for (int i = 0; i < 8; i++) {
    const int m = m0 + ty * 8 + i;
    const int n1 = n0 + tx * 4;
    float4* cp = (float4*)&C[(size_t)m * N_H + n1];
    float4 v;
    v.x = acc[i][0]; v.y = acc[i][1]; v.z = acc[i][2]; v.w = acc[i][3];
    if (!first) {
      const float4 o = *cp;
      v.x = __fadd_rn(o.x, v.x); v.y = __fadd_rn(o.y, v.y);
      v.z = __fadd_rn(o.z, v.z); v.w = __fadd_rn(o.w, v.w);
    }
    if (last) {
      v.x = __fadd_rn(v.x, bias[n1 + 0]); v.y = __fadd_rn(v.y, bias[n1 + 1]);
      v.z = __fadd_rn(v.z, bias[n1 + 2]); v.w = __fadd_rn(v.w, bias[n1 + 3]);
    }
    *cp = v;
  }
}

// ---------------------------------------------------------------------------
// Scan1: strict numpy op order (no fma): mem = ((0.9*mem) + cur) - reset.
// Spikes -> packed 64-bit ballot masks.
// ---------------------------------------------------------------------------
__global__ __launch_bounds__(256) void scan1_kernel(
    const float* __restrict__ cur1, unsigned long long* __restrict__ spkbits) {
  const int b = blockIdx.x >> 2;
  const int h = (blockIdx.x & 3) * 256 + threadIdx.x;
  const int lane = threadIdx.x & 63;
  const int word = h >> 6;  // 0..15
  float mem = 0.f;
  for (int t = 0; t < T_STEPS; ++t) {
    const float c = cur1[((size_t)t * BATCH + b) * N_H + h];
    const float reset = (mem > 1.0f) ? 1.0f : 0.0f;   // previous mem
    mem = __fsub_rn(__fadd_rn(__fmul_rn(0.9f, mem), c), reset);
    const unsigned long long msk = __ballot(mem > 1.0f);
    if (lane == 0) spkbits[((size_t)t * BATCH + b) * 16 + word] = msk;
  }
}

// ---------------------------------------------------------------------------
// cur2 (parallel over t,b,o): 3-panel k-ascending FMA chains —
// s1=[0,384), s2=[384,768), s3=[768,1024); cur2 = ((s1+s2)+s3) + b2[o].
// Block's bit-words staged once through LDS (removes 10x redundant reads).
// ---------------------------------------------------------------------------
__global__ __launch_bounds__(256) void cur2_kernel(
    const unsigned long long* __restrict__ spkbits,
    const float* __restrict__ W2, const float* __restrict__ b2,
    float* __restrict__ cur2) {
  __shared__ unsigned long long wlds[27][16];   // covers block's tb range
  const int g = blockIdx.x * 256 + threadIdx.x;   // ((t*256)+b)*10 + o
  const int tb = g / N_OUT;                       // t*256 + b
  const int o = g - tb * N_OUT;
  const int tb0 = (blockIdx.x * 256) / N_OUT;     // first tb in block
  // stage words for tb0 .. tb0+26 (27 rows x 16 words = 432 u64)
  for (int i = threadIdx.x; i < 27 * 16; i += 256) {
    const int trow = i >> 4;
    wlds[trow][i & 15] = spkbits[((size_t)(tb0 + trow)) * 16 + (i & 15)];
  }
  __syncthreads();
  const unsigned long long* w = wlds[tb - tb0];
  const float* W2o = &W2[(size_t)o * N_H];
  float s1 = 0.f, s2 = 0.f, s3 = 0.f;
#pragma unroll 8
  for (int h = 0; h < KC; ++h) {
    const float spk = ((w[h >> 6] >> (h & 63)) & 1ull) ? 1.0f : 0.0f;
    s1 = __builtin_fmaf(spk, W2o[h], s1);
  }
#pragma unroll 8
  for (int h = KC; h < 2 * KC; ++h) {
    const float spk = ((w[h >> 6] >> (h & 63)) & 1ull) ? 1.0f : 0.0f;
    s2 = __builtin_fmaf(spk, W2o[h], s2);
  }
#pragma unroll 8
  for (int h = 2 * KC; h < N_H; ++h) {
    const float spk = ((w[h >> 6] >> (h & 63)) & 1ull) ? 1.0f : 0.0f;
    s3 = __builtin_fmaf(spk, W2o[h], s3);
  }
  cur2[g] = __fadd_rn(__fadd_rn(__fadd_rn(s1, s2), s3), b2[o]);
}

// ---------------------------------------------------------------------------
// Scan2: strict mem2 scan over t per (b,o); writes spk2 + final mem2 (f32).
// ---------------------------------------------------------------------------
__global__ __launch_bounds__(256) void scan2_kernel(
    const float* __restrict__ cur2, float* __restrict__ out) {
  const int g = blockIdx.x * 256 + threadIdx.x;   // b*10 + o
  float m = 0.f;
  for (int t = 0; t < T_STEPS; ++t) {
    const float c = cur2[(size_t)t * (BATCH * N_OUT) + g];
    const float reset = (m > 1.0f) ? 1.0f : 0.0f;   // previous mem2
    m = __fsub_rn(__fadd_rn(__fmul_rn(0.9f, m), c), reset);
    out[(size_t)t * (BATCH * N_OUT) + g] = (m > 1.0f) ? 1.0f : 0.0f;
  }
  out[(size_t)T_STEPS * (BATCH * N_OUT) + g] = m;
}

// ---------------------------------------------------------------------------
extern "C" void kernel_launch(void* const* d_in, const int* in_sizes, int n_in,
                              void* d_out, int out_size, void* d_ws, size_t ws_size,
                              hipStream_t stream) {
  const float* x  = (const float*)d_in[0];   // [T, B, N_IN]  f32
  const float* W1 = (const float*)d_in[1];   // [N_H, N_IN]   f32
  const float* b1 = (const float*)d_in[2];   // [N_H]         f32
  const float* W2 = (const float*)d_in[3];   // [N_OUT, N_H]  f32
  const float* b2 = (const float*)d_in[4];   // [N_OUT]       f32
  float* out = (float*)d_out;  // f32: spk2[100,256,10] ++ mem2[256,10]

  // ws: cur1 f32 (104.9MB) | bits (3.3MB) | cur2 f32 (1.02MB)
  char* p = (char*)d_ws;
  float* cur1 = (float*)p;                           p += (size_t)M_TOT * N_H * 4;
  unsigned long long* bits = (unsigned long long*)p; p += (size_t)M_TOT * 16 * 8;
  float* cur2 = (float*)p;

  const int nblk = (M_TOT / 128) * (N_H / 128);   // 1600
  for (int ks = 0; ks < N_IN; ks += KC) {
    const int klen = (ks + KC <= N_IN) ? KC : (N_IN - ks);
    gemm1_panel<<<nblk, 512, 0, stream>>>(x, W1, b1, cur1, ks, klen,
                                          ks == 0 ? 1 : 0,
                                          (ks + klen == N_IN) ? 1 : 0);
  }
  scan1_kernel<<<BATCH * (N_H / 256), 256, 0, stream>>>(cur1, bits);
  cur2_kernel<<<(M_TOT * N_OUT) / 256, 256, 0, stream>>>(bits, W2, b2, cur2);
  scan2_kernel<<<(BATCH * N_OUT) / 256, 256, 0, stream>>>(cur2, out);
}

// Round 23
// 1500.946 us; speedup vs baseline: 2.8485x; 1.0309x over previous
//
#include <hip/hip_runtime.h>
#include <stdint.h>

#define T_STEPS 100
#define BATCH   256
#define N_IN    2048
#define N_H     1024
#define N_OUT   10
#define M_TOT   (T_STEPS * BATCH)   // 25600
#define KC      384                 // OpenBLAS SGEMM_DEFAULT_Q (Haswell/Zen)

// ---------------------------------------------------------------------------
// GEMM1 panel pass (one dispatch per KC panel; 6 total).
// Bit-exact contract (R9/R14/R16/R19/R20/R22-verified): per C element each
// panel is a k-ascending FMA register chain from 0; joins are one f32 add per
// panel boundary in pass order (C RMW between dispatches); bias after last.
// Tile 128m x 128n, BK=32, 256 threads, 16x4 microtile:
//   per k per wave: 1 gather b128 (B) feeds 64 FMAs (2x R20's ratio) +
//   4 broadcast b128 (A, 2 distinct addrs/wave) -> LDS pipe no longer at
//   parity with FMA pipes (the measured 46%-of-peak ceiling).
// acc 64 + frags ~20 + addr ~briefly -> ~110 VGPR -> launch_bounds(256,4):
//   cap 128 VGPR, 16 waves/CU, 4 blocks/CU (LDS 33.8 KB).
// XCD map: xcd=id&7 owns an m-strip; 8 n-tiles of an m-tile consecutive.
// ---------------------------------------------------------------------------
__global__ __launch_bounds__(256, 4) void gemm1_panel(
    const float* __restrict__ A, const float* __restrict__ Bm,
    const float* __restrict__ bias, float* __restrict__ C,
    int ks, int klen, int first, int last) {
  __shared__ float As[32][132];   // [k][m], +4 pad (16.9 KB)
  __shared__ float Bs[32][132];   // [k][n]          (16.9 KB)
  const int tid = threadIdx.x;
  const int id = blockIdx.x;
  const int xcd = id & 7;
  const int j = id >> 3;               // 0..199 sequential per XCD
  const int m0 = (xcd * 25 + (j >> 3)) * 128;
  const int n0 = (j & 7) * 128;
  const int tx = tid & 31;        // col group (4 cols)  -> n = n0 + tx*4
  const int ty = tid >> 5;        // row group (16 rows) -> m = m0 + ty*16

  float acc[16][4];
#pragma unroll
  for (int i = 0; i < 16; i++)
#pragma unroll
    for (int j2 = 0; j2 < 4; j2++) acc[i][j2] = 0.f;

  for (int kk = 0; kk < klen; kk += 32) {
    // stage A and B tiles (128x32 each): thread handles slots tid, tid+256
    // slot s: row = s>>2, col8 = (s&3)*8 (two float4s)
#pragma unroll
    for (int i2 = 0; i2 < 2; i2++) {
      const int s = tid + 256 * i2;
      const int row = s >> 2;
      const int c8 = (s & 3) * 8;
      const float4 av0 = *(const float4*)(&A[(size_t)(m0 + row) * N_IN + ks + kk + c8]);
      const float4 av1 = *(const float4*)(&A[(size_t)(m0 + row) * N_IN + ks + kk + c8 + 4]);
      As[c8 + 0][row] = av0.x; As[c8 + 1][row] = av0.y;
      As[c8 + 2][row] = av0.z; As[c8 + 3][row] = av0.w;
      As[c8 + 4][row] = av1.x; As[c8 + 5][row] = av1.y;
      As[c8 + 6][row] = av1.z; As[c8 + 7][row] = av1.w;
      const float4 bv0 = *(const float4*)(&Bm[(size_t)(n0 + row) * N_IN + ks + kk + c8]);
      const float4 bv1 = *(const float4*)(&Bm[(size_t)(n0 + row) * N_IN + ks + kk + c8 + 4]);
      Bs[c8 + 0][row] = bv0.x; Bs[c8 + 1][row] = bv0.y;
      Bs[c8 + 2][row] = bv0.z; Bs[c8 + 3][row] = bv0.w;
      Bs[c8 + 4][row] = bv1.x; Bs[c8 + 5][row] = bv1.y;
      Bs[c8 + 6][row] = bv1.z; Bs[c8 + 7][row] = bv1.w;
    }
    __syncthreads();
#pragma unroll
    for (int k = 0; k < 32; k++) {
      float a[16], b[4];
      *(float4*)&a[0]  = *(const float4*)&As[k][ty * 16];
      *(float4*)&a[4]  = *(const float4*)&As[k][ty * 16 + 4];
      *(float4*)&a[8]  = *(const float4*)&As[k][ty * 16 + 8];
      *(float4*)&a[12] = *(const float4*)&As[k][ty * 16 + 12];
      *(float4*)&b[0]  = *(const float4*)&Bs[k][tx * 4];
#pragma unroll
      for (int i = 0; i < 16; i++)
#pragma unroll
        for (int j2 = 0; j2 < 4; j2++)
          acc[i][j2] = __builtin_fmaf(a[i], b[j2], acc[i][j2]);
    }
    __syncthreads();
  }
  // epilogue: join with previous panels (one add), bias after last panel
#pragma unroll
  for (int i = 0; i < 16; i++) {
    const int m = m0 + ty * 16 + i;
    const int n1 = n0 + tx * 4;
    float4* cp = (float4*)&C[(size_t)m * N_H + n1];
    float4 v;
    v.x = acc[i][0]; v.y = acc[i][1]; v.z = acc[i][2]; v.w = acc[i][3];
    if (!first) {
      const float4 o = *cp;
      v.x = __fadd_rn(o.x, v.x); v.y = __fadd_rn(o.y, v.y);
      v.z = __fadd_rn(o.z, v.z); v.w = __fadd_rn(o.w, v.w);
    }
    if (last) {
      v.x = __fadd_rn(v.x, bias[n1 + 0]); v.y = __fadd_rn(v.y, bias[n1 + 1]);
      v.z = __fadd_rn(v.z, bias[n1 + 2]); v.w = __fadd_rn(v.w, bias[n1 + 3]);
    }
    *cp = v;
  }
}

// ---------------------------------------------------------------------------
// Scan1: strict numpy op order (no fma): mem = ((0.9*mem) + cur) - reset.
// Spikes -> packed 64-bit ballot masks.
// ---------------------------------------------------------------------------
__global__ __launch_bounds__(256) void scan1_kernel(
    const float* __restrict__ cur1, unsigned long long* __restrict__ spkbits) {
  const int b = blockIdx.x >> 2;
  const int h = (blockIdx.x & 3) * 256 + threadIdx.x;
  const int lane = threadIdx.x & 63;
  const int word = h >> 6;  // 0..15
  float mem = 0.f;
  for (int t = 0; t < T_STEPS; ++t) {
    const float c = cur1[((size_t)t * BATCH + b) * N_H + h];
    const float reset = (mem > 1.0f) ? 1.0f : 0.0f;   // previous mem
    mem = __fsub_rn(__fadd_rn(__fmul_rn(0.9f, mem), c), reset);
    const unsigned long long msk = __ballot(mem > 1.0f);
    if (lane == 0) spkbits[((size_t)t * BATCH + b) * 16 + word] = msk;
  }
}

// ---------------------------------------------------------------------------
// cur2 (parallel over t,b,o): 3-panel k-ascending FMA chains —
// s1=[0,384), s2=[384,768), s3=[768,1024); cur2 = ((s1+s2)+s3) + b2[o].
// Block's bit-words staged once through LDS.
// ---------------------------------------------------------------------------
__global__ __launch_bounds__(256) void cur2_kernel(
    const unsigned long long* __restrict__ spkbits,
    const float* __restrict__ W2, const float* __restrict__ b2,
    float* __restrict__ cur2) {
  __shared__ unsigned long long wlds[27][16];   // covers block's tb range
  const int g = blockIdx.x * 256 + threadIdx.x;   // ((t*256)+b)*10 + o
  const int tb = g / N_OUT;                       // t*256 + b
  const int o = g - tb * N_OUT;
  const int tb0 = (blockIdx.x * 256) / N_OUT;     // first tb in block
  for (int i = threadIdx.x; i < 27 * 16; i += 256) {
    const int trow = i >> 4;
    wlds[trow][i & 15] = spkbits[((size_t)(tb0 + trow)) * 16 + (i & 15)];
  }
  __syncthreads();
  const unsigned long long* w = wlds[tb - tb0];
  const float* W2o = &W2[(size_t)o * N_H];
  float s1 = 0.f, s2 = 0.f, s3 = 0.f;
#pragma unroll 8
  for (int h = 0; h < KC; ++h) {
    const float spk = ((w[h >> 6] >> (h & 63)) & 1ull) ? 1.0f : 0.0f;
    s1 = __builtin_fmaf(spk, W2o[h], s1);
  }
#pragma unroll 8
  for (int h = KC; h < 2 * KC; ++h) {
    const float spk = ((w[h >> 6] >> (h & 63)) & 1ull) ? 1.0f : 0.0f;
    s2 = __builtin_fmaf(spk, W2o[h], s2);
  }
#pragma unroll 8
  for (int h = 2 * KC; h < N_H; ++h) {
    const float spk = ((w[h >> 6] >> (h & 63)) & 1ull) ? 1.0f : 0.0f;
    s3 = __builtin_fmaf(spk, W2o[h], s3);
  }
  cur2[g] = __fadd_rn(__fadd_rn(__fadd_rn(s1, s2), s3), b2[o]);
}

// ---------------------------------------------------------------------------
// Scan2: strict mem2 scan over t per (b,o); writes spk2 + final mem2 (f32).
// ---------------------------------------------------------------------------
__global__ __launch_bounds__(256) void scan2_kernel(
    const float* __restrict__ cur2, float* __restrict__ out) {
  const int g = blockIdx.x * 256 + threadIdx.x;   // b*10 + o
  float m = 0.f;
  for (int t = 0; t < T_STEPS; ++t) {
    const float c = cur2[(size_t)t * (BATCH * N_OUT) + g];
    const float reset = (m > 1.0f) ? 1.0f : 0.0f;   // previous mem2
    m = __fsub_rn(__fadd_rn(__fmul_rn(0.9f, m), c), reset);
    out[(size_t)t * (BATCH * N_OUT) + g] = (m > 1.0f) ? 1.0f : 0.0f;
  }
  out[(size_t)T_STEPS * (BATCH * N_OUT) + g] = m;
}

// ---------------------------------------------------------------------------
extern "C" void kernel_launch(void* const* d_in, const int* in_sizes, int n_in,
                              void* d_out, int out_size, void* d_ws, size_t ws_size,
                              hipStream_t stream) {
  const float* x  = (const float*)d_in[0];   // [T, B, N_IN]  f32
  const float* W1 = (const float*)d_in[1];   // [N_H, N_IN]   f32
  const float* b1 = (const float*)d_in[2];   // [N_H]         f32
  const float* W2 = (const float*)d_in[3];   // [N_OUT, N_H]  f32
  const float* b2 = (const float*)d_in[4];   // [N_OUT]       f32
  float* out = (float*)d_out;  // f32: spk2[100,256,10] ++ mem2[256,10]

  // ws: cur1 f32 (104.9MB) | bits (3.3MB) | cur2 f32 (1.02MB)
  char* p = (char*)d_ws;
  float* cur1 = (float*)p;                           p += (size_t)M_TOT * N_H * 4;
  unsigned long long* bits = (unsigned long long*)p; p += (size_t)M_TOT * 16 * 8;
  float* cur2 = (float*)p;

  const int nblk = (M_TOT / 128) * (N_H / 128);   // 1600
  for (int ks = 0; ks < N_IN; ks += KC) {
    const int klen = (ks + KC <= N_IN) ? KC : (N_IN - ks);
    gemm1_panel<<<nblk, 256, 0, stream>>>(x, W1, b1, cur1, ks, klen,
                                          ks == 0 ? 1 : 0,
                                          (ks + klen == N_IN) ? 1 : 0);
  }
  scan1_kernel<<<BATCH * (N_H / 256), 256, 0, stream>>>(cur1, bits);
  cur2_kernel<<<(M_TOT * N_OUT) / 256, 256, 0, stream>>>(bits, W2, b2, cur2);
  scan2_kernel<<<(BATCH * N_OUT) / 256, 256, 0, stream>>>(cur2, out);
}